// Round 10
// baseline (237.271 us; speedup 1.0000x reference)
//
#include <hip/hip_runtime.h>
#include <hip/hip_bf16.h>

#define NN 50000      // nodes
#define NE 800000     // edges
#define NG 512        // graphs
#define HD 128        // hidden
#define EPS 1e-5f
#define L1B 196                 // coarse buckets (dst>>8)
#define EPB 4096                // edges per L1 bin block
#define NL1 ((NE + EPB - 1) / EPB)   // 196

typedef __attribute__((ext_vector_type(8))) short short8;
typedef __attribute__((ext_vector_type(4))) float f32x4;

__device__ __forceinline__ float bfu(unsigned short u) {
    return __uint_as_float((unsigned)u << 16);
}

// ---------------------------------------------------------------- init: zero + W-pack
// bpack[layer][2048 frags][8 bf16]; frag f: tile=f>>8, kk=(f>>6)&3, lane=f&63
__global__ __launch_bounds__(256) void k_init(int* __restrict__ gtot,
                                              float* __restrict__ pooled,
                                              const float* __restrict__ W0,
                                              const float* __restrict__ W1,
                                              const float* __restrict__ W2,
                                              __hip_bfloat16* __restrict__ bp) {
    const int i = blockIdx.x * 256 + threadIdx.x;
    if (i < L1B) gtot[i] = 0;
    if (i < NG * HD) pooled[i] = 0.f;
    if (i < 3 * 2048) {
        const int layer = i >> 11;
        const int f     = i & 2047;
        const int tile  = f >> 8, kk = (f >> 6) & 3, lane = f & 63;
        const int col   = tile * 16 + (lane & 15);
        const int kbase = kk * 32 + ((lane >> 4) << 3);
        const float* W  = (layer == 0) ? W0 : (layer == 1) ? W1 : W2;
        const int Klim  = (layer == 0) ? 100 : 128;
        alignas(16) __hip_bfloat16 o[8];
#pragma unroll
        for (int j = 0; j < 8; ++j) {
            const int k = kbase + j;
            o[j] = __float2bfloat16((k < Klim) ? W[(size_t)k * HD + col] : 0.f);
        }
        *(float4*)&bp[(size_t)i * 8] = *(const float4*)o;
    }
}

// ---------------------------------------------------------------- CSR build
// coarse histogram: 196 bins of 256 dst each, LDS-reduced
__global__ __launch_bounds__(256) void k_histL1(const int* __restrict__ dstv,
                                                int* __restrict__ gtot, int E) {
    __shared__ int h[L1B];
    const int t  = threadIdx.x;
    const int e0 = blockIdx.x * EPB;
    const int e1 = (e0 + EPB < E) ? (e0 + EPB) : E;
    for (int i = t; i < L1B; i += 256) h[i] = 0;
    __syncthreads();
    for (int e = e0 + t; e < e1; e += 256) atomicAdd(&h[dstv[e] >> 8], 1);
    __syncthreads();
    for (int i = t; i < L1B; i += 256)
        if (h[i]) atomicAdd(&gtot[i], h[i]);
}

// scan coarse totals -> gbase[0..196], gcursor copy; row_ptr[NN]=NE
__global__ __launch_bounds__(256) void k_scan196(const int* __restrict__ gtot,
                                                 int* __restrict__ gbase,
                                                 int* __restrict__ gcursor,
                                                 int* __restrict__ row_ptr) {
    __shared__ int s[256];
    const int t = threadIdx.x;
    const int v = (t < L1B) ? gtot[t] : 0;
    s[t] = v;
    __syncthreads();
    for (int off = 1; off < 256; off <<= 1) {
        int u = (t >= off) ? s[t - off] : 0;
        __syncthreads();
        s[t] += u;
        __syncthreads();
    }
    const int ex = s[t] - v;
    if (t < L1B) { gbase[t] = ex; gcursor[t] = ex; }
    if (t == 0) { gbase[L1B] = NE; row_ptr[NN] = NE; }
}

// ---- Level 1: bin edges into coarse-bucket regions of stage[], runs coalesced.
// element: x = (dst<<16)|src  (both < 65536), y = weight bits
__global__ __launch_bounds__(256) void k_binL1(const int* __restrict__ srcv,
                                               const int* __restrict__ dstv,
                                               const float* __restrict__ ewt,
                                               int* __restrict__ gcursor,
                                               int2* __restrict__ stage, int E) {
    __shared__ int hist[L1B], lstart[L1B], gbase[L1B], lcur[L1B];
    __shared__ int s[256];
    __shared__ int2 lsort[EPB];          // 32 KB
    const int t  = threadIdx.x;
    const int e0 = blockIdx.x * EPB;
    const int e1 = (e0 + EPB < E) ? (e0 + EPB) : E;
    for (int i = t; i < L1B; i += 256) hist[i] = 0;
    __syncthreads();
    for (int e = e0 + t; e < e1; e += 256)
        atomicAdd(&hist[dstv[e] >> 8], 1);
    __syncthreads();
    {
        const int v = (t < L1B) ? hist[t] : 0;
        s[t] = v;
        __syncthreads();
        for (int off = 1; off < 256; off <<= 1) {
            int u = (t >= off) ? s[t - off] : 0;
            __syncthreads();
            s[t] += u;
            __syncthreads();
        }
        if (t < L1B) {
            const int ex = s[t] - v;
            lstart[t] = ex;
            lcur[t]   = ex;
            gbase[t]  = v ? atomicAdd(&gcursor[t], v) : 0;
        }
    }
    __syncthreads();
    for (int e = e0 + t; e < e1; e += 256) {
        const int d = dstv[e];
        const int r = atomicAdd(&lcur[d >> 8], 1);
        lsort[r] = make_int2((d << 16) | srcv[e], __float_as_int(ewt[e]));
    }
    __syncthreads();
    const int n = e1 - e0;
    for (int i = t; i < n; i += 256) {
        const int2 el = lsort[i];
        const unsigned b = ((unsigned)el.x) >> 24;     // dst>>8
        stage[gbase[b] + (i - lstart[b])] = el;
    }
}

// ---- Level 2: one block per bucket; local count+scan -> row_ptr + placement
// cw element: (src<<16) | bf16(weight)
__global__ __launch_bounds__(256) void k_binL2(const int2* __restrict__ stage,
                                               const int* __restrict__ gbase,
                                               int* __restrict__ row_ptr,
                                               unsigned* __restrict__ cw) {
    __shared__ int cnt[256], s[256], cur[256];
    const int t    = threadIdx.x;
    const int b    = blockIdx.x;
    const int d0   = b << 8;
    const int nd   = (NN - d0 < 256) ? (NN - d0) : 256;
    const int base = gbase[b];
    const int end  = gbase[b + 1];
    cnt[t] = 0;
    __syncthreads();
    for (int i = base + t; i < end; i += 256) {
        const unsigned dst = ((unsigned)stage[i].x) >> 16;
        atomicAdd(&cnt[dst - d0], 1);
    }
    __syncthreads();
    {   // exclusive scan of cnt
        const int v = cnt[t];
        s[t] = v;
        __syncthreads();
        for (int off = 1; off < 256; off <<= 1) {
            int u = (t >= off) ? s[t - off] : 0;
            __syncthreads();
            s[t] += u;
            __syncthreads();
        }
        const int ex = base + s[t] - v;
        cur[t] = ex;
        if (t < nd) row_ptr[d0 + t] = ex;
    }
    __syncthreads();
    for (int i = base + t; i < end; i += 256) {
        const int2 el = stage[i];
        const unsigned dst = ((unsigned)el.x) >> 16;
        const int p = atomicAdd(&cur[dst - d0], 1);
        __hip_bfloat16 hw16 = __float2bfloat16(__int_as_float(el.y));
        const unsigned wb = *reinterpret_cast<const unsigned short*>(&hw16);
        cw[p] = (((unsigned)el.x & 0xFFFFu) << 16) | wb;
    }
}

// ------------------------------------------------- MFMA core (shared epilogue)
__device__ __forceinline__ void mfma_gemm_store(const __hip_bfloat16 (*hb)[136],
                                                const __hip_bfloat16* __restrict__ bp,
                                                __hip_bfloat16* __restrict__ hwb,
                                                int t, int r0) {
    const int wave = t >> 6, lane = t & 63;
    const int rw   = wave * 16;
    const int arow = rw + (lane & 15);
    const int acol = ((lane >> 4) << 3);
    short8 a[4];
#pragma unroll
    for (int kk = 0; kk < 4; ++kk)
        a[kk] = *(const short8*)&hb[arow][kk * 32 + acol];

    f32x4 acc[8] = {};
    const short8* bfr = (const short8*)bp;
#pragma unroll
    for (int tile = 0; tile < 8; ++tile) {
#pragma unroll
        for (int kk = 0; kk < 4; ++kk) {
            const short8 bb = bfr[(tile * 4 + kk) * 64 + lane];
            acc[tile] = __builtin_amdgcn_mfma_f32_16x16x32_bf16(a[kk], bb, acc[tile], 0, 0, 0);
        }
    }
    const int baser = r0 + rw + ((lane >> 4) << 2);
    const int bcol  = lane & 15;
#pragma unroll
    for (int tile = 0; tile < 8; ++tile) {
        const int col = tile * 16 + bcol;
#pragma unroll
        for (int j = 0; j < 4; ++j) {
            const int row = baser + j;
            if (row < NN) hwb[(size_t)row * HD + col] = __float2bfloat16(acc[tile][j]);
        }
    }
}

// ---- layer 0: fp32 input (K=100, zero-padded to 128)
__global__ __launch_bounds__(256, 3) void k_ln_gemm_f32(const float* __restrict__ hin,
                                                        const float* __restrict__ g,
                                                        const float* __restrict__ b,
                                                        const __hip_bfloat16* __restrict__ bp,
                                                        __hip_bfloat16* __restrict__ hwb) {
    constexpr int K  = 100;
    constexpr int SK = K + 4;
    __shared__ float hs[64][SK];              // 26.6 KB
    __shared__ __hip_bfloat16 hb[64][136];    // 17.4 KB
    const int t  = threadIdx.x;
    const int r0 = blockIdx.x * 64;
    {
        const float4* src4 = (const float4*)(hin + (size_t)r0 * K);
        const int valid_rows = (NN - r0 < 64) ? (NN - r0) : 64;
        const int maxf = valid_rows * K;
        for (int i = t; i < 64 * K / 4; i += 256) {
            int f = i * 4;
            float4 v = (f < maxf) ? src4[i] : make_float4(0.f, 0.f, 0.f, 0.f);
            int r = f / K, k = f - r * K;
            *(float4*)&hs[r][k] = v;
        }
    }
    __syncthreads();
    {
        const int row = t >> 2, l = t & 3;
        float s = 0.f, s2 = 0.f;
        for (int k = l; k < K; k += 4) { float v = hs[row][k]; s += v; s2 += v * v; }
        s  += __shfl_xor(s, 1);  s2 += __shfl_xor(s2, 1);
        s  += __shfl_xor(s, 2);  s2 += __shfl_xor(s2, 2);
        const float mean = s / (float)K;
        const float var  = s2 / (float)K - mean * mean;
        const float rstd = rsqrtf(var + EPS);
        for (int k = l; k < K; k += 4)
            hb[row][k] = __float2bfloat16((hs[row][k] - mean) * rstd * g[k] + b[k]);
        for (int k = K + l; k < 128; k += 4)
            hb[row][k] = __float2bfloat16(0.f);
    }
    __syncthreads();
    mfma_gemm_store(hb, bp, hwb, t, r0);
}

// ---- layers 1,2: bf16 input (K=128), LN in-place in bf16 LDS
__global__ __launch_bounds__(256, 4) void k_ln_gemm_b16(const __hip_bfloat16* __restrict__ hin,
                                                        const float* __restrict__ g,
                                                        const float* __restrict__ b,
                                                        const __hip_bfloat16* __restrict__ bp,
                                                        __hip_bfloat16* __restrict__ hwb) {
    __shared__ __hip_bfloat16 hb[64][136];    // 17.4 KB only
    const int t  = threadIdx.x;
    const int r0 = blockIdx.x * 64;
    {
        const float4* src4 = (const float4*)(hin + (size_t)r0 * HD);  // 8 bf16 per float4
        const int valid_rows = (NN - r0 < 64) ? (NN - r0) : 64;
        const int maxv = valid_rows * 16;     // float4s
        for (int i = t; i < 1024; i += 256) {
            float4 v = (i < maxv) ? src4[i] : make_float4(0.f, 0.f, 0.f, 0.f);
            const int r = i >> 4, k = (i & 15) * 8;
            *(float4*)&hb[r][k] = v;
        }
    }
    __syncthreads();
    {
        const int row = t >> 2, l = t & 3;
        float s = 0.f, s2 = 0.f;
        for (int k = l; k < 128; k += 4) {
            const float v = __bfloat162float(hb[row][k]);
            s += v; s2 += v * v;
        }
        s  += __shfl_xor(s, 1);  s2 += __shfl_xor(s2, 1);
        s  += __shfl_xor(s, 2);  s2 += __shfl_xor(s2, 2);
        const float mean = s / 128.f;
        const float var  = s2 / 128.f - mean * mean;
        const float rstd = rsqrtf(var + EPS);
        for (int k = l; k < 128; k += 4)
            hb[row][k] = __float2bfloat16((__bfloat162float(hb[row][k]) - mean) * rstd * g[k] + b[k]);
    }
    __syncthreads();
    mfma_gemm_store(hb, bp, hwb, t, r0);
}

// ------------------------------------------------- CSR gather + bias + relu
// cw: (src<<16)|bf16w; 16 independent row-gathers in flight; NT edge loads.
__device__ __forceinline__ float4 agg_row(const __hip_bfloat16* __restrict__ hwb,
                                          const unsigned* __restrict__ cw,
                                          const float* __restrict__ bias,
                                          int e0, int e1, size_t coff) {
    float4 acc = {0.f, 0.f, 0.f, 0.f};
    int e = e0;
    for (; e + 16 <= e1; e += 16) {
        unsigned c[16];
#pragma unroll
        for (int j = 0; j < 16; ++j) c[j] = __builtin_nontemporal_load(&cw[e + j]);
        ushort4 r[16];
#pragma unroll
        for (int j = 0; j < 16; ++j)
            r[j] = *(const ushort4*)(hwb + (size_t)(c[j] >> 16) * HD + coff);
#pragma unroll
        for (int j = 0; j < 16; ++j) {
            const float w = bfu((unsigned short)(c[j] & 0xFFFFu));
            acc.x += w * bfu(r[j].x);
            acc.y += w * bfu(r[j].y);
            acc.z += w * bfu(r[j].z);
            acc.w += w * bfu(r[j].w);
        }
    }
    if (e + 8 <= e1) {
        unsigned c[8];
#pragma unroll
        for (int j = 0; j < 8; ++j) c[j] = __builtin_nontemporal_load(&cw[e + j]);
        ushort4 r[8];
#pragma unroll
        for (int j = 0; j < 8; ++j)
            r[j] = *(const ushort4*)(hwb + (size_t)(c[j] >> 16) * HD + coff);
#pragma unroll
        for (int j = 0; j < 8; ++j) {
            const float w = bfu((unsigned short)(c[j] & 0xFFFFu));
            acc.x += w * bfu(r[j].x);
            acc.y += w * bfu(r[j].y);
            acc.z += w * bfu(r[j].z);
            acc.w += w * bfu(r[j].w);
        }
        e += 8;
    }
    if (e + 4 <= e1) {
        unsigned c[4];
#pragma unroll
        for (int j = 0; j < 4; ++j) c[j] = __builtin_nontemporal_load(&cw[e + j]);
        ushort4 r[4];
#pragma unroll
        for (int j = 0; j < 4; ++j)
            r[j] = *(const ushort4*)(hwb + (size_t)(c[j] >> 16) * HD + coff);
#pragma unroll
        for (int j = 0; j < 4; ++j) {
            const float w = bfu((unsigned short)(c[j] & 0xFFFFu));
            acc.x += w * bfu(r[j].x);
            acc.y += w * bfu(r[j].y);
            acc.z += w * bfu(r[j].z);
            acc.w += w * bfu(r[j].w);
        }
        e += 4;
    }
    for (; e < e1; ++e) {
        const unsigned c = cw[e];
        const float w = bfu((unsigned short)(c & 0xFFFFu));
        const ushort4 rv = *(const ushort4*)(hwb + (size_t)(c >> 16) * HD + coff);
        acc.x += w * bfu(rv.x);
        acc.y += w * bfu(rv.y);
        acc.z += w * bfu(rv.z);
        acc.w += w * bfu(rv.w);
    }
    const float4 bb = *(const float4*)(bias + coff);
    float4 o;
    o.x = fmaxf(acc.x + bb.x, 0.f);
    o.y = fmaxf(acc.y + bb.y, 0.f);
    o.z = fmaxf(acc.z + bb.z, 0.f);
    o.w = fmaxf(acc.w + bb.w, 0.f);
    return o;
}

// layers 0,1: gather + bias + relu -> bf16 activations
__global__ __launch_bounds__(256) void k_aggregate(const __hip_bfloat16* __restrict__ hwb,
                                                   const int* __restrict__ row_ptr,
                                                   const unsigned* __restrict__ cw,
                                                   const float* __restrict__ bias,
                                                   __hip_bfloat16* __restrict__ hout, int n) {
    const int t    = threadIdx.x;
    const int grp  = t >> 5;
    const int lane = t & 31;
    const int node = blockIdx.x * 8 + grp;
    if (node >= n) return;
    const size_t coff = (size_t)lane * 4;
    float4 o = agg_row(hwb, cw, bias, row_ptr[node], row_ptr[node + 1], coff);
    alignas(8) __hip_bfloat16 ob[4] = {
        __float2bfloat16(o.x), __float2bfloat16(o.y),
        __float2bfloat16(o.z), __float2bfloat16(o.w)};
    *(ushort4*)(hout + (size_t)node * HD + coff) = *(const ushort4*)ob;
}

// layer 2: gather + bias + relu, then per-block graph-run reduction into pooled
__global__ __launch_bounds__(256) void k_aggpool(const __hip_bfloat16* __restrict__ hwb,
                                                 const int* __restrict__ row_ptr,
                                                 const unsigned* __restrict__ cw,
                                                 const float* __restrict__ bias,
                                                 const int* __restrict__ batch,
                                                 float* __restrict__ pooled, int n) {
    __shared__ float lds[8][128];
    __shared__ int gof[8];
    const int t    = threadIdx.x;
    const int grp  = t >> 5;
    const int lane = t & 31;
    const int node = blockIdx.x * 8 + grp;
    const size_t coff = (size_t)lane * 4;
    float4 o = {0.f, 0.f, 0.f, 0.f};
    if (node < n)
        o = agg_row(hwb, cw, bias, row_ptr[node], row_ptr[node + 1], coff);
    *(float4*)&lds[grp][lane * 4] = o;
    if (lane == 0) gof[grp] = (node < n) ? batch[node] : -1;
    __syncthreads();
    if (t < 128) {
        float sum = 0.f;
        int curg = gof[0];
#pragma unroll
        for (int r = 0; r < 8; ++r) {
            const int gr = gof[r];
            if (gr != curg) {
                if (curg >= 0) atomicAdd(&pooled[curg * HD + t], sum);
                sum = 0.f;
                curg = gr;
            }
            if (gr >= 0) sum += lds[r][t];
        }
        if (curg >= 0) atomicAdd(&pooled[curg * HD + t], sum);
    }
}

// ------------------------------------------------- final: pooled/cnt @ Wlin + blin
__global__ __launch_bounds__(128) void k_linout(const float* __restrict__ pooled,
                                                const int* __restrict__ batch,
                                                const float* __restrict__ Wlin,
                                                const float* __restrict__ blin,
                                                float* __restrict__ out, int n) {
    __shared__ float red[2][128];
    const int gph = blockIdx.x;
    const int c   = threadIdx.x;
    int lo = 0, hi = n;
    while (lo < hi) { int mid = (lo + hi) >> 1; if (batch[mid] < gph) lo = mid + 1; else hi = mid; }
    const int start = lo;
    hi = n;
    while (lo < hi) { int mid = (lo + hi) >> 1; if (batch[mid] < gph + 1) lo = mid + 1; else hi = mid; }
    const float cnt = (float)(lo - start);
    const float pv = pooled[gph * HD + c] / fmaxf(cnt, 1.0f);
    red[0][c] = pv * Wlin[c * 2 + 0];
    red[1][c] = pv * Wlin[c * 2 + 1];
    __syncthreads();
    for (int off = 64; off; off >>= 1) {
        if (c < off) { red[0][c] += red[0][c + off]; red[1][c] += red[1][c + off]; }
        __syncthreads();
    }
    if (c == 0) {
        out[gph * 2 + 0] = red[0][0] + blin[0];
        out[gph * 2 + 1] = red[1][0] + blin[1];
    }
}

// ---------------------------------------------------------------- launch
extern "C" void kernel_launch(void* const* d_in, const int* in_sizes, int n_in,
                              void* d_out, int out_size, void* d_ws, size_t ws_size,
                              hipStream_t stream) {
    const float* x     = (const float*)d_in[0];
    const int*   ei    = (const int*)d_in[1];     // [2][E]
    const float* ewt   = (const float*)d_in[2];
    const int*   batch = (const int*)d_in[3];
    const float* ln_g0 = (const float*)d_in[4];
    const float* ln_b0 = (const float*)d_in[5];
    const float* ln_g1 = (const float*)d_in[6];
    const float* ln_b1 = (const float*)d_in[7];
    const float* ln_g2 = (const float*)d_in[8];
    const float* ln_b2 = (const float*)d_in[9];
    const float* W0    = (const float*)d_in[10];
    const float* b0    = (const float*)d_in[11];
    const float* W1    = (const float*)d_in[12];
    const float* b1    = (const float*)d_in[13];
    const float* W2    = (const float*)d_in[14];
    const float* b2    = (const float*)d_in[15];
    const float* Wlin  = (const float*)d_in[16];
    const float* blin  = (const float*)d_in[17];
    float* out = (float*)d_out;

    const int* srcv = ei;
    const int* dstv = ei + NE;

    // workspace carve-up (256B aligned)
    char* ws = (char*)d_ws;
    size_t o = 0;
    auto carve = [&](size_t bytes) { void* p = ws + o; o += (bytes + 255) & ~(size_t)255; return p; };
    int*      row_ptr = (int*)carve(sizeof(int) * (NN + 1));
    int*      gtot    = (int*)carve(sizeof(int) * L1B);
    int*      gbase   = (int*)carve(sizeof(int) * (L1B + 1));
    int*      gcursor = (int*)carve(sizeof(int) * L1B);
    float*    pooled  = (float*)carve(sizeof(float) * NG * HD);
    unsigned* cw      = (unsigned*)carve(sizeof(unsigned) * NE);
    int2*     stage   = (int2*)carve(sizeof(int2) * NE);
    __hip_bfloat16* bpack = (__hip_bfloat16*)carve(sizeof(__hip_bfloat16) * 3 * 2048 * 8);
    __hip_bfloat16* hwb   = (__hip_bfloat16*)carve(sizeof(__hip_bfloat16) * NN * HD);
    __hip_bfloat16* hA    = (__hip_bfloat16*)carve(sizeof(__hip_bfloat16) * NN * HD);
    __hip_bfloat16* hB    = (__hip_bfloat16*)carve(sizeof(__hip_bfloat16) * NN * HD);
    (void)ws_size; (void)n_in; (void)in_sizes; (void)out_size;

    // init: zero gtot+pooled, pack W fragments (one dispatch)
    k_init<<<257, 256, 0, stream>>>(gtot, pooled, W0, W1, W2, bpack);

    // CSR build: coarse hist -> tiny scan -> two-level placement (+row_ptr)
    k_histL1<<<NL1, 256, 0, stream>>>(dstv, gtot, NE);
    k_scan196<<<1, 256, 0, stream>>>(gtot, gbase, gcursor, row_ptr);
    k_binL1<<<NL1, 256, 0, stream>>>(srcv, dstv, ewt, gcursor, stage, NE);
    k_binL2<<<L1B, 256, 0, stream>>>(stage, gbase, row_ptr, cw);

    const int GEMM_GRID = (NN + 63) / 64;   // 782
    const int AGG_GRID  = (NN + 7) / 8;

    // layer 0
    k_ln_gemm_f32<<<GEMM_GRID, 256, 0, stream>>>(x, ln_g0, ln_b0, bpack, hwb);
    k_aggregate<<<AGG_GRID, 256, 0, stream>>>(hwb, row_ptr, cw, b0, hA, NN);
    // layer 1
    k_ln_gemm_b16<<<GEMM_GRID, 256, 0, stream>>>(hA, ln_g1, ln_b1, bpack + 2048 * 8, hwb);
    k_aggregate<<<AGG_GRID, 256, 0, stream>>>(hwb, row_ptr, cw, b1, hB, NN);
    // layer 2: aggregate fused with mean-pool accumulation
    k_ln_gemm_b16<<<GEMM_GRID, 256, 0, stream>>>(hB, ln_g2, ln_b2, bpack + 2 * 2048 * 8, hwb);
    k_aggpool<<<AGG_GRID, 256, 0, stream>>>(hwb, row_ptr, cw, b2, batch, pooled, NN);
    // classifier
    k_linout<<<NG, 128, 0, stream>>>(pooled, batch, Wlin, blin, out, NN);
}

// Round 11
// 207.237 us; speedup vs baseline: 1.1449x; 1.1449x over previous
//
#include <hip/hip_runtime.h>
#include <hip/hip_bf16.h>

#define NN 50000      // nodes
#define NE 800000     // edges
#define NG 512        // graphs
#define HD 128        // hidden
#define EPS 1e-5f
#define L1B 196                 // coarse buckets (dst>>8)
#define EPB 4096                // edges per L1 bin block
#define NL1 ((NE + EPB - 1) / EPB)   // 196

typedef __attribute__((ext_vector_type(8))) short short8;
typedef __attribute__((ext_vector_type(4))) float f32x4;

__device__ __forceinline__ float bfu(unsigned short u) {
    return __uint_as_float((unsigned)u << 16);
}

// ---------------------------------------------------------------- init: zero + W-pack
// bpack[layer][2048 frags][8 bf16]; frag f: tile=f>>8, kk=(f>>6)&3, lane=f&63
__global__ __launch_bounds__(256) void k_init(int* __restrict__ gtot,
                                              float* __restrict__ pooled,
                                              const float* __restrict__ W0,
                                              const float* __restrict__ W1,
                                              const float* __restrict__ W2,
                                              __hip_bfloat16* __restrict__ bp) {
    const int i = blockIdx.x * 256 + threadIdx.x;
    if (i < L1B) gtot[i] = 0;
    if (i < NG * HD) pooled[i] = 0.f;
    if (i < 3 * 2048) {
        const int layer = i >> 11;
        const int f     = i & 2047;
        const int tile  = f >> 8, kk = (f >> 6) & 3, lane = f & 63;
        const int col   = tile * 16 + (lane & 15);
        const int kbase = kk * 32 + ((lane >> 4) << 3);
        const float* W  = (layer == 0) ? W0 : (layer == 1) ? W1 : W2;
        const int Klim  = (layer == 0) ? 100 : 128;
        alignas(16) __hip_bfloat16 o[8];
#pragma unroll
        for (int j = 0; j < 8; ++j) {
            const int k = kbase + j;
            o[j] = __float2bfloat16((k < Klim) ? W[(size_t)k * HD + col] : 0.f);
        }
        *(float4*)&bp[(size_t)i * 8] = *(const float4*)o;
    }
}

// ---------------------------------------------------------------- CSR build
// coarse histogram: 196 bins of 256 dst each, LDS-reduced
__global__ __launch_bounds__(256) void k_histL1(const int* __restrict__ dstv,
                                                int* __restrict__ gtot, int E) {
    __shared__ int h[L1B];
    const int t  = threadIdx.x;
    const int e0 = blockIdx.x * EPB;
    const int e1 = (e0 + EPB < E) ? (e0 + EPB) : E;
    for (int i = t; i < L1B; i += 256) h[i] = 0;
    __syncthreads();
    for (int e = e0 + t; e < e1; e += 256) atomicAdd(&h[dstv[e] >> 8], 1);
    __syncthreads();
    for (int i = t; i < L1B; i += 256)
        if (h[i]) atomicAdd(&gtot[i], h[i]);
}

// scan coarse totals -> gbase[0..196], gcursor copy; row_ptr[NN]=NE
__global__ __launch_bounds__(256) void k_scan196(const int* __restrict__ gtot,
                                                 int* __restrict__ gbase,
                                                 int* __restrict__ gcursor,
                                                 int* __restrict__ row_ptr) {
    __shared__ int s[256];
    const int t = threadIdx.x;
    const int v = (t < L1B) ? gtot[t] : 0;
    s[t] = v;
    __syncthreads();
    for (int off = 1; off < 256; off <<= 1) {
        int u = (t >= off) ? s[t - off] : 0;
        __syncthreads();
        s[t] += u;
        __syncthreads();
    }
    const int ex = s[t] - v;
    if (t < L1B) { gbase[t] = ex; gcursor[t] = ex; }
    if (t == 0) { gbase[L1B] = NE; row_ptr[NN] = NE; }
}

// ---- Level 1: bin edges into coarse-bucket regions of stage[], runs coalesced.
// element: x = (dst<<16)|src  (both < 65536), y = weight bits
__global__ __launch_bounds__(256) void k_binL1(const int* __restrict__ srcv,
                                               const int* __restrict__ dstv,
                                               const float* __restrict__ ewt,
                                               int* __restrict__ gcursor,
                                               int2* __restrict__ stage, int E) {
    __shared__ int hist[L1B], lstart[L1B], gbase[L1B], lcur[L1B];
    __shared__ int s[256];
    __shared__ int2 lsort[EPB];          // 32 KB
    const int t  = threadIdx.x;
    const int e0 = blockIdx.x * EPB;
    const int e1 = (e0 + EPB < E) ? (e0 + EPB) : E;
    for (int i = t; i < L1B; i += 256) hist[i] = 0;
    __syncthreads();
    for (int e = e0 + t; e < e1; e += 256)
        atomicAdd(&hist[dstv[e] >> 8], 1);
    __syncthreads();
    {
        const int v = (t < L1B) ? hist[t] : 0;
        s[t] = v;
        __syncthreads();
        for (int off = 1; off < 256; off <<= 1) {
            int u = (t >= off) ? s[t - off] : 0;
            __syncthreads();
            s[t] += u;
            __syncthreads();
        }
        if (t < L1B) {
            const int ex = s[t] - v;
            lstart[t] = ex;
            lcur[t]   = ex;
            gbase[t]  = v ? atomicAdd(&gcursor[t], v) : 0;
        }
    }
    __syncthreads();
    for (int e = e0 + t; e < e1; e += 256) {
        const int d = dstv[e];
        const int r = atomicAdd(&lcur[d >> 8], 1);
        lsort[r] = make_int2((d << 16) | srcv[e], __float_as_int(ewt[e]));
    }
    __syncthreads();
    const int n = e1 - e0;
    for (int i = t; i < n; i += 256) {
        const int2 el = lsort[i];
        const unsigned b = ((unsigned)el.x) >> 24;     // dst>>8
        stage[gbase[b] + (i - lstart[b])] = el;
    }
}

// ---- Level 2: one block per bucket; local count+scan -> row_ptr + placement
// cw element: int2{src, f32 weight bits}  (R8-proven layout)
__global__ __launch_bounds__(256) void k_binL2(const int2* __restrict__ stage,
                                               const int* __restrict__ gbase,
                                               int* __restrict__ row_ptr,
                                               int2* __restrict__ cw) {
    __shared__ int cnt[256], s[256], cur[256];
    const int t    = threadIdx.x;
    const int b    = blockIdx.x;
    const int d0   = b << 8;
    const int nd   = (NN - d0 < 256) ? (NN - d0) : 256;
    const int base = gbase[b];
    const int end  = gbase[b + 1];
    cnt[t] = 0;
    __syncthreads();
    for (int i = base + t; i < end; i += 256) {
        const unsigned dst = ((unsigned)stage[i].x) >> 16;
        atomicAdd(&cnt[dst - d0], 1);
    }
    __syncthreads();
    {   // exclusive scan of cnt
        const int v = cnt[t];
        s[t] = v;
        __syncthreads();
        for (int off = 1; off < 256; off <<= 1) {
            int u = (t >= off) ? s[t - off] : 0;
            __syncthreads();
            s[t] += u;
            __syncthreads();
        }
        const int ex = base + s[t] - v;
        cur[t] = ex;
        if (t < nd) row_ptr[d0 + t] = ex;
    }
    __syncthreads();
    for (int i = base + t; i < end; i += 256) {
        const int2 el = stage[i];
        const unsigned dst = ((unsigned)el.x) >> 16;
        const int p = atomicAdd(&cur[dst - d0], 1);
        cw[p] = make_int2(el.x & 0xFFFF, el.y);
    }
}

// ------------------------------------------------- MFMA core (shared epilogue)
__device__ __forceinline__ void mfma_gemm_store(const __hip_bfloat16 (*hb)[136],
                                                const __hip_bfloat16* __restrict__ bp,
                                                __hip_bfloat16* __restrict__ hwb,
                                                int t, int r0) {
    const int wave = t >> 6, lane = t & 63;
    const int rw   = wave * 16;
    const int arow = rw + (lane & 15);
    const int acol = ((lane >> 4) << 3);
    short8 a[4];
#pragma unroll
    for (int kk = 0; kk < 4; ++kk)
        a[kk] = *(const short8*)&hb[arow][kk * 32 + acol];

    f32x4 acc[8] = {};
    const short8* bfr = (const short8*)bp;
#pragma unroll
    for (int tile = 0; tile < 8; ++tile) {
#pragma unroll
        for (int kk = 0; kk < 4; ++kk) {
            const short8 bb = bfr[(tile * 4 + kk) * 64 + lane];
            acc[tile] = __builtin_amdgcn_mfma_f32_16x16x32_bf16(a[kk], bb, acc[tile], 0, 0, 0);
        }
    }
    const int baser = r0 + rw + ((lane >> 4) << 2);
    const int bcol  = lane & 15;
#pragma unroll
    for (int tile = 0; tile < 8; ++tile) {
        const int col = tile * 16 + bcol;
#pragma unroll
        for (int j = 0; j < 4; ++j) {
            const int row = baser + j;
            if (row < NN) hwb[(size_t)row * HD + col] = __float2bfloat16(acc[tile][j]);
        }
    }
}

// ---- layer 0: fp32 input (K=100, zero-padded to 128)
__global__ __launch_bounds__(256, 3) void k_ln_gemm_f32(const float* __restrict__ hin,
                                                        const float* __restrict__ g,
                                                        const float* __restrict__ b,
                                                        const __hip_bfloat16* __restrict__ bp,
                                                        __hip_bfloat16* __restrict__ hwb) {
    constexpr int K  = 100;
    constexpr int SK = K + 4;
    __shared__ float hs[64][SK];              // 26.6 KB
    __shared__ __hip_bfloat16 hb[64][136];    // 17.4 KB
    const int t  = threadIdx.x;
    const int r0 = blockIdx.x * 64;
    {
        const float4* src4 = (const float4*)(hin + (size_t)r0 * K);
        const int valid_rows = (NN - r0 < 64) ? (NN - r0) : 64;
        const int maxf = valid_rows * K;
        for (int i = t; i < 64 * K / 4; i += 256) {
            int f = i * 4;
            float4 v = (f < maxf) ? src4[i] : make_float4(0.f, 0.f, 0.f, 0.f);
            int r = f / K, k = f - r * K;
            *(float4*)&hs[r][k] = v;
        }
    }
    __syncthreads();
    {
        const int row = t >> 2, l = t & 3;
        float s = 0.f, s2 = 0.f;
        for (int k = l; k < K; k += 4) { float v = hs[row][k]; s += v; s2 += v * v; }
        s  += __shfl_xor(s, 1);  s2 += __shfl_xor(s2, 1);
        s  += __shfl_xor(s, 2);  s2 += __shfl_xor(s2, 2);
        const float mean = s / (float)K;
        const float var  = s2 / (float)K - mean * mean;
        const float rstd = rsqrtf(var + EPS);
        for (int k = l; k < K; k += 4)
            hb[row][k] = __float2bfloat16((hs[row][k] - mean) * rstd * g[k] + b[k]);
        for (int k = K + l; k < 128; k += 4)
            hb[row][k] = __float2bfloat16(0.f);
    }
    __syncthreads();
    mfma_gemm_store(hb, bp, hwb, t, r0);
}

// ---- layers 1,2: bf16 input (K=128), LN in-place in bf16 LDS
__global__ __launch_bounds__(256, 4) void k_ln_gemm_b16(const __hip_bfloat16* __restrict__ hin,
                                                        const float* __restrict__ g,
                                                        const float* __restrict__ b,
                                                        const __hip_bfloat16* __restrict__ bp,
                                                        __hip_bfloat16* __restrict__ hwb) {
    __shared__ __hip_bfloat16 hb[64][136];    // 17.4 KB only
    const int t  = threadIdx.x;
    const int r0 = blockIdx.x * 64;
    {
        const float4* src4 = (const float4*)(hin + (size_t)r0 * HD);  // 8 bf16 per float4
        const int valid_rows = (NN - r0 < 64) ? (NN - r0) : 64;
        const int maxv = valid_rows * 16;     // float4s
        for (int i = t; i < 1024; i += 256) {
            float4 v = (i < maxv) ? src4[i] : make_float4(0.f, 0.f, 0.f, 0.f);
            const int r = i >> 4, k = (i & 15) * 8;
            *(float4*)&hb[r][k] = v;
        }
    }
    __syncthreads();
    {
        const int row = t >> 2, l = t & 3;
        float s = 0.f, s2 = 0.f;
        for (int k = l; k < 128; k += 4) {
            const float v = __bfloat162float(hb[row][k]);
            s += v; s2 += v * v;
        }
        s  += __shfl_xor(s, 1);  s2 += __shfl_xor(s2, 1);
        s  += __shfl_xor(s, 2);  s2 += __shfl_xor(s2, 2);
        const float mean = s / 128.f;
        const float var  = s2 / 128.f - mean * mean;
        const float rstd = rsqrtf(var + EPS);
        for (int k = l; k < 128; k += 4)
            hb[row][k] = __float2bfloat16((__bfloat162float(hb[row][k]) - mean) * rstd * g[k] + b[k]);
    }
    __syncthreads();
    mfma_gemm_store(hb, bp, hwb, t, r0);
}

// ------------------------------------------------- CSR gather + bias + relu
// R8-proven loop: int2 edges, plain cached loads, MLP=8
__device__ __forceinline__ float4 agg_row(const __hip_bfloat16* __restrict__ hwb,
                                          const int2* __restrict__ cw,
                                          const float* __restrict__ bias,
                                          int e0, int e1, size_t coff) {
    float4 acc = {0.f, 0.f, 0.f, 0.f};
    int e = e0;
    for (; e + 8 <= e1; e += 8) {
        int2 c[8];
#pragma unroll
        for (int j = 0; j < 8; ++j) c[j] = cw[e + j];
        ushort4 r[8];
#pragma unroll
        for (int j = 0; j < 8; ++j)
            r[j] = *(const ushort4*)(hwb + (size_t)c[j].x * HD + coff);
#pragma unroll
        for (int j = 0; j < 8; ++j) {
            const float w = __int_as_float(c[j].y);
            acc.x += w * bfu(r[j].x);
            acc.y += w * bfu(r[j].y);
            acc.z += w * bfu(r[j].z);
            acc.w += w * bfu(r[j].w);
        }
    }
    if (e + 4 <= e1) {
        int2 c[4];
#pragma unroll
        for (int j = 0; j < 4; ++j) c[j] = cw[e + j];
        ushort4 r[4];
#pragma unroll
        for (int j = 0; j < 4; ++j)
            r[j] = *(const ushort4*)(hwb + (size_t)c[j].x * HD + coff);
#pragma unroll
        for (int j = 0; j < 4; ++j) {
            const float w = __int_as_float(c[j].y);
            acc.x += w * bfu(r[j].x);
            acc.y += w * bfu(r[j].y);
            acc.z += w * bfu(r[j].z);
            acc.w += w * bfu(r[j].w);
        }
        e += 4;
    }
    for (; e < e1; ++e) {
        const int2 c = cw[e];
        const float w = __int_as_float(c.y);
        const ushort4 rv = *(const ushort4*)(hwb + (size_t)c.x * HD + coff);
        acc.x += w * bfu(rv.x);
        acc.y += w * bfu(rv.y);
        acc.z += w * bfu(rv.z);
        acc.w += w * bfu(rv.w);
    }
    const float4 bb = *(const float4*)(bias + coff);
    float4 o;
    o.x = fmaxf(acc.x + bb.x, 0.f);
    o.y = fmaxf(acc.y + bb.y, 0.f);
    o.z = fmaxf(acc.z + bb.z, 0.f);
    o.w = fmaxf(acc.w + bb.w, 0.f);
    return o;
}

// layers 0,1: gather + bias + relu -> bf16 activations
__global__ __launch_bounds__(256) void k_aggregate(const __hip_bfloat16* __restrict__ hwb,
                                                   const int* __restrict__ row_ptr,
                                                   const int2* __restrict__ cw,
                                                   const float* __restrict__ bias,
                                                   __hip_bfloat16* __restrict__ hout, int n) {
    const int t    = threadIdx.x;
    const int grp  = t >> 5;
    const int lane = t & 31;
    const int node = blockIdx.x * 8 + grp;
    if (node >= n) return;
    const size_t coff = (size_t)lane * 4;
    float4 o = agg_row(hwb, cw, bias, row_ptr[node], row_ptr[node + 1], coff);
    alignas(8) __hip_bfloat16 ob[4] = {
        __float2bfloat16(o.x), __float2bfloat16(o.y),
        __float2bfloat16(o.z), __float2bfloat16(o.w)};
    *(ushort4*)(hout + (size_t)node * HD + coff) = *(const ushort4*)ob;
}

// layer 2: gather + bias + relu, then per-block graph-run reduction into pooled
__global__ __launch_bounds__(256) void k_aggpool(const __hip_bfloat16* __restrict__ hwb,
                                                 const int* __restrict__ row_ptr,
                                                 const int2* __restrict__ cw,
                                                 const float* __restrict__ bias,
                                                 const int* __restrict__ batch,
                                                 float* __restrict__ pooled, int n) {
    __shared__ float lds[8][128];
    __shared__ int gof[8];
    const int t    = threadIdx.x;
    const int grp  = t >> 5;
    const int lane = t & 31;
    const int node = blockIdx.x * 8 + grp;
    const size_t coff = (size_t)lane * 4;
    float4 o = {0.f, 0.f, 0.f, 0.f};
    if (node < n)
        o = agg_row(hwb, cw, bias, row_ptr[node], row_ptr[node + 1], coff);
    *(float4*)&lds[grp][lane * 4] = o;
    if (lane == 0) gof[grp] = (node < n) ? batch[node] : -1;
    __syncthreads();
    if (t < 128) {
        float sum = 0.f;
        int curg = gof[0];
#pragma unroll
        for (int r = 0; r < 8; ++r) {
            const int gr = gof[r];
            if (gr != curg) {
                if (curg >= 0) atomicAdd(&pooled[curg * HD + t], sum);
                sum = 0.f;
                curg = gr;
            }
            if (gr >= 0) sum += lds[r][t];
        }
        if (curg >= 0) atomicAdd(&pooled[curg * HD + t], sum);
    }
}

// ------------------------------------------------- final: pooled/cnt @ Wlin + blin
__global__ __launch_bounds__(128) void k_linout(const float* __restrict__ pooled,
                                                const int* __restrict__ batch,
                                                const float* __restrict__ Wlin,
                                                const float* __restrict__ blin,
                                                float* __restrict__ out, int n) {
    __shared__ float red[2][128];
    const int gph = blockIdx.x;
    const int c   = threadIdx.x;
    int lo = 0, hi = n;
    while (lo < hi) { int mid = (lo + hi) >> 1; if (batch[mid] < gph) lo = mid + 1; else hi = mid; }
    const int start = lo;
    hi = n;
    while (lo < hi) { int mid = (lo + hi) >> 1; if (batch[mid] < gph + 1) lo = mid + 1; else hi = mid; }
    const float cnt = (float)(lo - start);
    const float pv = pooled[gph * HD + c] / fmaxf(cnt, 1.0f);
    red[0][c] = pv * Wlin[c * 2 + 0];
    red[1][c] = pv * Wlin[c * 2 + 1];
    __syncthreads();
    for (int off = 64; off; off >>= 1) {
        if (c < off) { red[0][c] += red[0][c + off]; red[1][c] += red[1][c + off]; }
        __syncthreads();
    }
    if (c == 0) {
        out[gph * 2 + 0] = red[0][0] + blin[0];
        out[gph * 2 + 1] = red[1][0] + blin[1];
    }
}

// ---------------------------------------------------------------- launch
extern "C" void kernel_launch(void* const* d_in, const int* in_sizes, int n_in,
                              void* d_out, int out_size, void* d_ws, size_t ws_size,
                              hipStream_t stream) {
    const float* x     = (const float*)d_in[0];
    const int*   ei    = (const int*)d_in[1];     // [2][E]
    const float* ewt   = (const float*)d_in[2];
    const int*   batch = (const int*)d_in[3];
    const float* ln_g0 = (const float*)d_in[4];
    const float* ln_b0 = (const float*)d_in[5];
    const float* ln_g1 = (const float*)d_in[6];
    const float* ln_b1 = (const float*)d_in[7];
    const float* ln_g2 = (const float*)d_in[8];
    const float* ln_b2 = (const float*)d_in[9];
    const float* W0    = (const float*)d_in[10];
    const float* b0    = (const float*)d_in[11];
    const float* W1    = (const float*)d_in[12];
    const float* b1    = (const float*)d_in[13];
    const float* W2    = (const float*)d_in[14];
    const float* b2    = (const float*)d_in[15];
    const float* Wlin  = (const float*)d_in[16];
    const float* blin  = (const float*)d_in[17];
    float* out = (float*)d_out;

    const int* srcv = ei;
    const int* dstv = ei + NE;

    // workspace carve-up (256B aligned)
    char* ws = (char*)d_ws;
    size_t o = 0;
    auto carve = [&](size_t bytes) { void* p = ws + o; o += (bytes + 255) & ~(size_t)255; return p; };
    int*   row_ptr = (int*)carve(sizeof(int) * (NN + 1));
    int*   gtot    = (int*)carve(sizeof(int) * L1B);
    int*   gbase   = (int*)carve(sizeof(int) * (L1B + 1));
    int*   gcursor = (int*)carve(sizeof(int) * L1B);
    float* pooled  = (float*)carve(sizeof(float) * NG * HD);
    int2*  cw      = (int2*)carve(sizeof(int2) * NE);
    int2*  stage   = (int2*)carve(sizeof(int2) * NE);
    __hip_bfloat16* bpack = (__hip_bfloat16*)carve(sizeof(__hip_bfloat16) * 3 * 2048 * 8);
    __hip_bfloat16* hwb   = (__hip_bfloat16*)carve(sizeof(__hip_bfloat16) * NN * HD);
    __hip_bfloat16* hA    = (__hip_bfloat16*)carve(sizeof(__hip_bfloat16) * NN * HD);
    __hip_bfloat16* hB    = (__hip_bfloat16*)carve(sizeof(__hip_bfloat16) * NN * HD);
    (void)ws_size; (void)n_in; (void)in_sizes; (void)out_size;

    // init: zero gtot+pooled, pack W fragments (one dispatch)
    k_init<<<257, 256, 0, stream>>>(gtot, pooled, W0, W1, W2, bpack);

    // CSR build: coarse hist -> tiny scan -> two-level placement (+row_ptr)
    k_histL1<<<NL1, 256, 0, stream>>>(dstv, gtot, NE);
    k_scan196<<<1, 256, 0, stream>>>(gtot, gbase, gcursor, row_ptr);
    k_binL1<<<NL1, 256, 0, stream>>>(srcv, dstv, ewt, gcursor, stage, NE);
    k_binL2<<<L1B, 256, 0, stream>>>(stage, gbase, row_ptr, cw);

    const int GEMM_GRID = (NN + 63) / 64;   // 782
    const int AGG_GRID  = (NN + 7) / 8;

    // layer 0
    k_ln_gemm_f32<<<GEMM_GRID, 256, 0, stream>>>(x, ln_g0, ln_b0, bpack, hwb);
    k_aggregate<<<AGG_GRID, 256, 0, stream>>>(hwb, row_ptr, cw, b0, hA, NN);
    // layer 1
    k_ln_gemm_b16<<<GEMM_GRID, 256, 0, stream>>>(hA, ln_g1, ln_b1, bpack + 2048 * 8, hwb);
    k_aggregate<<<AGG_GRID, 256, 0, stream>>>(hwb, row_ptr, cw, b1, hB, NN);
    // layer 2: aggregate fused with mean-pool accumulation
    k_ln_gemm_b16<<<GEMM_GRID, 256, 0, stream>>>(hB, ln_g2, ln_b2, bpack + 2 * 2048 * 8, hwb);
    k_aggpool<<<AGG_GRID, 256, 0, stream>>>(hwb, row_ptr, cw, b2, batch, pooled, NN);
    // classifier
    k_linout<<<NG, 128, 0, stream>>>(pooled, batch, Wlin, blin, out, NN);
}